// Round 1
// baseline (760.733 us; speedup 1.0000x reference)
//
#include <hip/hip_runtime.h>
#include <hip/hip_bf16.h>
#include <math.h>

#define B_ 16
#define T_ 4096
#define D_ 1024
#define U_ 1024
#define M_ (B_*T_)   // 65536

typedef __attribute__((ext_vector_type(8))) short short8;
typedef __attribute__((ext_vector_type(4))) float float4v;

static __device__ __forceinline__ short f2bf(float f) {
    unsigned u = __builtin_bit_cast(unsigned, f);
    u += 0x7FFFu + ((u >> 16) & 1u);   // RNE
    return (short)(u >> 16);
}

// ---------------- kernel 1: hb[b][u] = sum_k h[b][k]*W1[k][u] + b1[u] + b2[u]
__global__ void hb_kernel(const float* __restrict__ h, const float* __restrict__ W1,
                          const float* __restrict__ b1, const float* __restrict__ b2,
                          float* __restrict__ hb) {
    int gid = blockIdx.x * 256 + threadIdx.x;    // 16384 total
    int b = gid >> 10, u = gid & 1023;
    const float* hr = h + b * D_;
    const float* w = W1 + u;
    float s0 = 0.f, s1 = 0.f, s2 = 0.f, s3 = 0.f;
    for (int k = 0; k < D_; k += 4) {
        s0 += hr[k+0] * w[(size_t)(k+0) * U_];
        s1 += hr[k+1] * w[(size_t)(k+1) * U_];
        s2 += hr[k+2] * w[(size_t)(k+2) * U_];
        s3 += hr[k+3] * w[(size_t)(k+3) * U_];
    }
    hb[gid] = b1[u] + b2[u] + ((s0 + s1) + (s2 + s3));
}

// ---------------- kernel 2: fused GEMM (enc @ W2) + tanh(+hb) dot V -> score partials
// grid (512 mtiles, 8 ntiles), 256 threads. Tile 128x128, BK=32, bf16 MFMA 16x16x32.
__global__ __launch_bounds__(256) void gemm_score_kernel(
    const float* __restrict__ A,    // enc [M_, D_]
    const float* __restrict__ W2,   // [D_, U_]
    const float* __restrict__ hb,   // [B_, U_]
    const float* __restrict__ V,    // [U_]
    float* __restrict__ scorepart)  // [8][M_]
{
    __shared__ __align__(16) short As[128 * 32];
    __shared__ __align__(16) short Bs[128 * 32];
    __shared__ float sbuf[2][128];

    const int tid = threadIdx.x;
    const int mtile = blockIdx.x, ntile = blockIdx.y;
    const int row0 = mtile * 128, n0 = ntile * 128;
    const int bidx = row0 >> 12;     // row0 / T_, one batch per M-tile (128 | 4096)

    const int lane = tid & 63, wv = tid >> 6;
    const int wm = wv >> 1, wn = wv & 1;
    const int lm = lane & 15, quad = lane >> 4;

    float4v acc[4][4] = {};

    for (int K0 = 0; K0 < D_; K0 += 32) {
        // stage A: 128 rows x 32 k, fp32 -> bf16, b128 LDS writes
        #pragma unroll
        for (int i = 0; i < 2; ++i) {
            int g = tid + i * 256;            // 0..511
            int row = g >> 2, kq = (g & 3) * 8;
            const float4v* p = (const float4v*)(A + (size_t)(row0 + row) * D_ + K0 + kq);
            float4v f0 = p[0], f1 = p[1];
            short8 v;
            v[0]=f2bf(f0[0]); v[1]=f2bf(f0[1]); v[2]=f2bf(f0[2]); v[3]=f2bf(f0[3]);
            v[4]=f2bf(f1[0]); v[5]=f2bf(f1[1]); v[6]=f2bf(f1[2]); v[7]=f2bf(f1[3]);
            *(short8*)&As[row * 32 + kq] = v;
        }
        // stage B transposed: Bs[n][k] from W2[k][n] (coalesced dword reads along n)
        #pragma unroll
        for (int i = 0; i < 2; ++i) {
            int g = tid + i * 256;            // 0..511
            int n = g & 127, kq = (g >> 7) * 8;
            const float* p = W2 + (size_t)(K0 + kq) * U_ + n0 + n;
            short8 v;
            #pragma unroll
            for (int j = 0; j < 8; ++j) v[j] = f2bf(p[(size_t)j * U_]);
            *(short8*)&Bs[n * 32 + kq] = v;
        }
        __syncthreads();
        short8 af[4], bfr[4];
        #pragma unroll
        for (int mi = 0; mi < 4; ++mi)
            af[mi] = *(const short8*)&As[(wm * 64 + mi * 16 + lm) * 32 + quad * 8];
        #pragma unroll
        for (int ni = 0; ni < 4; ++ni)
            bfr[ni] = *(const short8*)&Bs[(wn * 64 + ni * 16 + lm) * 32 + quad * 8];
        #pragma unroll
        for (int mi = 0; mi < 4; ++mi)
            #pragma unroll
            for (int ni = 0; ni < 4; ++ni)
                acc[mi][ni] = __builtin_amdgcn_mfma_f32_16x16x32_bf16(
                    af[mi], bfr[ni], acc[mi][ni], 0, 0, 0);
        __syncthreads();
    }

    // epilogue: score partial over this block's 128 columns
    float hbv[4], Vv[4];
    #pragma unroll
    for (int ni = 0; ni < 4; ++ni) {
        int U = n0 + wn * 64 + ni * 16 + lm;
        hbv[ni] = hb[bidx * U_ + U];
        Vv[ni]  = V[U];
    }
    #pragma unroll
    for (int mi = 0; mi < 4; ++mi) {
        #pragma unroll
        for (int r = 0; r < 4; ++r) {
            float s = 0.f;
            #pragma unroll
            for (int ni = 0; ni < 4; ++ni)
                s += tanhf(acc[mi][ni][r] + hbv[ni]) * Vv[ni];
            #pragma unroll
            for (int off = 1; off < 16; off <<= 1)
                s += __shfl_xor(s, off, 64);      // reduce the 16 lanes of a row
            if (lm == 0)
                sbuf[wn][wm * 64 + mi * 16 + quad * 4 + r] = s;
        }
    }
    __syncthreads();
    if (tid < 128)
        scorepart[(size_t)ntile * M_ + row0 + tid] = sbuf[0][tid] + sbuf[1][tid];
}

// ---------------- kernel 3: per-batch softmax over T
__global__ void softmax_kernel(const float* __restrict__ scorepart,
                               const float* __restrict__ bv,
                               float* __restrict__ out_attn) {   // d_out + 16384
    __shared__ float sm[T_];
    __shared__ float red[4];
    int b = blockIdx.x, tid = threadIdx.x;
    float bvv = bv[0];
    float lmax = -1e30f;
    for (int i = 0; i < 16; ++i) {
        int t = tid + i * 256;
        float s = bvv;
        #pragma unroll
        for (int p = 0; p < 8; ++p) s += scorepart[(size_t)p * M_ + b * T_ + t];
        sm[t] = s;
        lmax = fmaxf(lmax, s);
    }
    #pragma unroll
    for (int off = 1; off < 64; off <<= 1) lmax = fmaxf(lmax, __shfl_xor(lmax, off, 64));
    int wv = tid >> 6;
    if ((tid & 63) == 0) red[wv] = lmax;
    __syncthreads();
    lmax = fmaxf(fmaxf(red[0], red[1]), fmaxf(red[2], red[3]));
    float lsum = 0.f;
    for (int i = 0; i < 16; ++i) {
        int t = tid + i * 256;
        float e = __expf(sm[t] - lmax);
        sm[t] = e;
        lsum += e;
    }
    #pragma unroll
    for (int off = 1; off < 64; off <<= 1) lsum += __shfl_xor(lsum, off, 64);
    __syncthreads();
    if ((tid & 63) == 0) red[wv] = lsum;
    __syncthreads();
    float rinv = 1.f / ((red[0] + red[1]) + (red[2] + red[3]));
    for (int i = 0; i < 16; ++i) {
        int t = tid + i * 256;
        out_attn[b * T_ + t] = sm[t] * rinv;
    }
}

// ---------------- kernel 4: context partials over T-chunks of 256
__global__ void ctx_part_kernel(const float* __restrict__ enc,
                                const float* __restrict__ attn,  // d_out + 16384
                                float* __restrict__ part) {      // [256][1024]
    __shared__ float wsm[256];
    int x = blockIdx.x;              // x = tc*16 + b
    int b = x & 15, tc = x >> 4;
    int tid = threadIdx.x;
    wsm[tid] = attn[b * T_ + tc * 256 + tid];
    __syncthreads();
    const float* e0 = enc + ((size_t)(b * T_ + tc * 256)) * D_ + tid * 4;
    float4v acc = {};
    for (int t = 0; t < 256; ++t) {
        float4v v = *(const float4v*)(e0 + (size_t)t * D_);
        acc += wsm[t] * v;
    }
    *(float4v*)(part + (size_t)x * 1024 + tid * 4) = acc;
}

// ---------------- kernel 5: reduce context partials
__global__ void ctx_reduce_kernel(const float* __restrict__ part, float* __restrict__ ctx) {
    int gid = blockIdx.x * 256 + threadIdx.x;   // 0..16383
    int b = gid >> 10, d = gid & 1023;
    float s = 0.f;
    #pragma unroll
    for (int tc = 0; tc < 16; ++tc) s += part[(size_t)(tc * 16 + b) * 1024 + d];
    ctx[gid] = s;
}

extern "C" void kernel_launch(void* const* d_in, const int* in_sizes, int n_in,
                              void* d_out, int out_size, void* d_ws, size_t ws_size,
                              hipStream_t stream) {
    const float* h   = (const float*)d_in[0];
    const float* enc = (const float*)d_in[1];
    const float* W1  = (const float*)d_in[2];
    const float* b1  = (const float*)d_in[3];
    const float* W2  = (const float*)d_in[4];
    const float* b2  = (const float*)d_in[5];
    const float* V   = (const float*)d_in[6];
    const float* bv  = (const float*)d_in[7];
    float* out = (float*)d_out;                 // [0,16384) context, [16384,81920) attn
    float* ws  = (float*)d_ws;
    float* hb        = ws;                      // 16384 floats
    float* scorepart = ws + 16384;              // 8 * 65536 floats
    float* ctxpart   = ws + 16384 + 8 * 65536;  // 256 * 1024 floats

    hb_kernel<<<64, 256, 0, stream>>>(h, W1, b1, b2, hb);
    gemm_score_kernel<<<dim3(512, 8), 256, 0, stream>>>(enc, W2, hb, V, scorepart);
    softmax_kernel<<<16, 256, 0, stream>>>(scorepart, bv, out + 16384);
    ctx_part_kernel<<<256, 256, 0, stream>>>(enc, out + 16384, ctxpart);
    ctx_reduce_kernel<<<64, 256, 0, stream>>>(ctxpart, out);
}

// Round 3
// 622.372 us; speedup vs baseline: 1.2223x; 1.2223x over previous
//
#include <hip/hip_runtime.h>
#include <hip/hip_bf16.h>
#include <math.h>

#define B_ 16
#define T_ 4096
#define D_ 1024
#define U_ 1024
#define M_ (B_*T_)   // 65536

typedef __attribute__((ext_vector_type(8))) short short8;
typedef __attribute__((ext_vector_type(4))) short short4v;
typedef __attribute__((ext_vector_type(4))) float float4v;

static __device__ __forceinline__ short f2bf(float f) {
    unsigned u = __builtin_bit_cast(unsigned, f);
    u += 0x7FFFu + ((u >> 16) & 1u);   // RNE
    return (short)(u >> 16);
}
static __device__ __forceinline__ float bf2f(short s) {
    unsigned u = ((unsigned)(unsigned short)s) << 16;
    return __builtin_bit_cast(float, u);
}
static __device__ __forceinline__ float fast_tanh(float x) {
    float c = fminf(fmaxf(2.f * x, -30.f), 30.f);
    float t = __expf(c);
    return __fdividef(t - 1.f, t + 1.f);
}

#define GLLDS(GP, LP) __builtin_amdgcn_global_load_lds( \
    (const __attribute__((address_space(1))) void*)(GP), \
    (__attribute__((address_space(3))) void*)(LP), 16, 0, 0)

// ---------------- kernel 1: hb partials, K split 4 ways
__global__ void hb_kernel(const float* __restrict__ h, const float* __restrict__ W1,
                          const float* __restrict__ b1, const float* __restrict__ b2,
                          float* __restrict__ hbp) {
    int x = blockIdx.x;                       // 256
    int kc = x >> 6;                          // 0..3
    int gid = (x & 63) * 256 + threadIdx.x;   // 0..16383
    int b = gid >> 10, u = gid & 1023;
    const float* hr = h + b * D_ + kc * 256;
    const float* w = W1 + (size_t)(kc * 256) * U_ + u;
    float s0 = 0.f, s1 = 0.f, s2 = 0.f, s3 = 0.f;
    for (int k = 0; k < 256; k += 4) {
        s0 += hr[k+0] * w[(size_t)(k+0) * U_];
        s1 += hr[k+1] * w[(size_t)(k+1) * U_];
        s2 += hr[k+2] * w[(size_t)(k+2) * U_];
        s3 += hr[k+3] * w[(size_t)(k+3) * U_];
    }
    float s = ((s0 + s1) + (s2 + s3));
    if (kc == 0) s += b1[u] + b2[u];
    hbp[kc * 16384 + gid] = s;
}

// ---------------- converters
__global__ void convert_enc(const float* __restrict__ enc, short* __restrict__ encbf) {
    size_t g = (size_t)blockIdx.x * 256 + threadIdx.x;   // 4M threads x 16 elems
    const float4v* p = (const float4v*)(enc + g * 16);
    float4v f0 = p[0], f1 = p[1], f2 = p[2], f3 = p[3];
    short8 a, b;
    a[0]=f2bf(f0[0]); a[1]=f2bf(f0[1]); a[2]=f2bf(f0[2]); a[3]=f2bf(f0[3]);
    a[4]=f2bf(f1[0]); a[5]=f2bf(f1[1]); a[6]=f2bf(f1[2]); a[7]=f2bf(f1[3]);
    b[0]=f2bf(f2[0]); b[1]=f2bf(f2[1]); b[2]=f2bf(f2[2]); b[3]=f2bf(f2[3]);
    b[4]=f2bf(f3[0]); b[5]=f2bf(f3[1]); b[6]=f2bf(f3[2]); b[7]=f2bf(f3[3]);
    short8* q = (short8*)(encbf + g * 16);
    q[0] = a; q[1] = b;
}

__global__ void convert_w2t(const float* __restrict__ W2, short* __restrict__ W2T) {
    __shared__ short t[64][65];
    int k0 = (blockIdx.x >> 4) * 64, u0 = (blockIdx.x & 15) * 64;
    int tx = threadIdx.x & 63, ty = threadIdx.x >> 6;   // ty 0..3
    #pragma unroll
    for (int r = 0; r < 16; ++r) {
        int kk = ty * 16 + r;
        t[kk][tx] = f2bf(W2[(size_t)(k0 + kk) * U_ + u0 + tx]);
    }
    __syncthreads();
    #pragma unroll
    for (int r = 0; r < 16; ++r) {
        int uu = ty * 16 + r;
        W2T[(size_t)(u0 + uu) * D_ + k0 + tx] = t[tx][uu];
    }
}

// ---------------- kernel 2: m97-style bf16 GEMM + tanh·V epilogue
__global__ __launch_bounds__(256) void gemm_score_bf16(
    const short* __restrict__ Abf,   // enc bf16 [M_, D_]
    const short* __restrict__ W2T,   // bf16 [U_, D_]
    const float* __restrict__ hbp,   // [4][B_, U_]
    const float* __restrict__ V,
    float* __restrict__ scorepart)   // [8][M_]
{
    __shared__ __align__(16) short As[128 * 32];
    __shared__ __align__(16) short Bs[128 * 32];
    __shared__ float sbuf[2][128];

    const int tid = threadIdx.x;
    const int ntile = blockIdx.x, mtile = blockIdx.y;
    const int row0 = mtile * 128, n0 = ntile * 128;
    const int bidx = row0 >> 12;

    const int lane = tid & 63, wv = tid >> 6;
    const int wm = wv >> 1, wn = wv & 1;
    const int lm = lane & 15, quad = lane >> 4;
    const int arow = tid >> 2, akq = (tid & 3) * 8;

    float4v acc[4][4] = {};

    for (int K0 = 0; K0 < D_; K0 += 32) {
        GLLDS(Abf + (size_t)(row0 + arow) * D_ + K0 + akq,       As + tid * 8);
        GLLDS(Abf + (size_t)(row0 + 64 + arow) * D_ + K0 + akq,  As + 2048 + tid * 8);
        GLLDS(W2T + (size_t)(n0 + arow) * D_ + K0 + akq,         Bs + tid * 8);
        GLLDS(W2T + (size_t)(n0 + 64 + arow) * D_ + K0 + akq,    Bs + 2048 + tid * 8);
        __syncthreads();
        short8 af[4], bfr[4];
        #pragma unroll
        for (int mi = 0; mi < 4; ++mi)
            af[mi] = *(const short8*)&As[(wm * 64 + mi * 16 + lm) * 32 + quad * 8];
        #pragma unroll
        for (int ni = 0; ni < 4; ++ni)
            bfr[ni] = *(const short8*)&Bs[(wn * 64 + ni * 16 + lm) * 32 + quad * 8];
        #pragma unroll
        for (int mi = 0; mi < 4; ++mi)
            #pragma unroll
            for (int ni = 0; ni < 4; ++ni)
                acc[mi][ni] = __builtin_amdgcn_mfma_f32_16x16x32_bf16(
                    af[mi], bfr[ni], acc[mi][ni], 0, 0, 0);
        __syncthreads();
    }

    float hbv[4], Vv[4];
    #pragma unroll
    for (int ni = 0; ni < 4; ++ni) {
        int U = n0 + wn * 64 + ni * 16 + lm;
        int o = bidx * U_ + U;
        hbv[ni] = hbp[o] + hbp[16384 + o] + hbp[32768 + o] + hbp[49152 + o];
        Vv[ni]  = V[U];
    }
    #pragma unroll
    for (int mi = 0; mi < 4; ++mi) {
        #pragma unroll
        for (int r = 0; r < 4; ++r) {
            float s = 0.f;
            #pragma unroll
            for (int ni = 0; ni < 4; ++ni)
                s += fast_tanh(acc[mi][ni][r] + hbv[ni]) * Vv[ni];
            #pragma unroll
            for (int off = 1; off < 16; off <<= 1)
                s += __shfl_xor(s, off, 64);
            if (lm == 0)
                sbuf[wn][wm * 64 + mi * 16 + quad * 4 + r] = s;
        }
    }
    __syncthreads();
    if (tid < 128)
        scorepart[(size_t)ntile * M_ + row0 + tid] = sbuf[0][tid] + sbuf[1][tid];
}

// ---------------- kernel 3: per-batch softmax over T
__global__ void softmax_kernel(const float* __restrict__ scorepart,
                               const float* __restrict__ bv,
                               float* __restrict__ out_attn) {
    __shared__ float sm[T_];
    __shared__ float red[4];
    int b = blockIdx.x, tid = threadIdx.x;
    float bvv = bv[0];
    float lmax = -1e30f;
    for (int i = 0; i < 16; ++i) {
        int t = tid + i * 256;
        float s = bvv;
        #pragma unroll
        for (int p = 0; p < 8; ++p) s += scorepart[(size_t)p * M_ + b * T_ + t];
        sm[t] = s;
        lmax = fmaxf(lmax, s);
    }
    #pragma unroll
    for (int off = 1; off < 64; off <<= 1) lmax = fmaxf(lmax, __shfl_xor(lmax, off, 64));
    int wv = tid >> 6;
    if ((tid & 63) == 0) red[wv] = lmax;
    __syncthreads();
    lmax = fmaxf(fmaxf(red[0], red[1]), fmaxf(red[2], red[3]));
    float lsum = 0.f;
    for (int i = 0; i < 16; ++i) {
        int t = tid + i * 256;
        float e = __expf(sm[t] - lmax);
        sm[t] = e;
        lsum += e;
    }
    #pragma unroll
    for (int off = 1; off < 64; off <<= 1) lsum += __shfl_xor(lsum, off, 64);
    __syncthreads();
    if ((tid & 63) == 0) red[wv] = lsum;
    __syncthreads();
    float rinv = 1.f / ((red[0] + red[1]) + (red[2] + red[3]));
    for (int i = 0; i < 16; ++i) {
        int t = tid + i * 256;
        out_attn[b * T_ + t] = sm[t] * rinv;
    }
}

// ---------------- kernel 4: context partials from bf16 enc
// 256 threads x 4 bf16 elems = exactly one D=1024 row per t. (R2 bug: 8/thread
// overran the row AND block x+1's partial region -> race. Fixed to 4/thread.)
__global__ void ctx_part_bf(const short* __restrict__ encbf,
                            const float* __restrict__ attn,
                            float* __restrict__ part) {
    __shared__ float wsm[256];
    int x = blockIdx.x;
    int b = x & 15, tc = x >> 4;
    int tid = threadIdx.x;
    wsm[tid] = attn[b * T_ + tc * 256 + tid];
    __syncthreads();
    const short* e0 = encbf + (size_t)(b * T_ + tc * 256) * D_ + tid * 4;
    float4v acc = {};
    for (int t = 0; t < 256; ++t) {
        short4v v = *(const short4v*)(e0 + (size_t)t * D_);
        float w = wsm[t];
        acc[0] += w * bf2f(v[0]);
        acc[1] += w * bf2f(v[1]);
        acc[2] += w * bf2f(v[2]);
        acc[3] += w * bf2f(v[3]);
    }
    *(float4v*)(part + (size_t)x * 1024 + tid * 4) = acc;
}

// ---------------- kernel 5: reduce context partials
__global__ void ctx_reduce_kernel(const float* __restrict__ part, float* __restrict__ ctx) {
    int gid = blockIdx.x * 256 + threadIdx.x;
    int b = gid >> 10, d = gid & 1023;
    float s = 0.f;
    #pragma unroll
    for (int tc = 0; tc < 16; ++tc) s += part[(size_t)(tc * 16 + b) * 1024 + d];
    ctx[gid] = s;
}

extern "C" void kernel_launch(void* const* d_in, const int* in_sizes, int n_in,
                              void* d_out, int out_size, void* d_ws, size_t ws_size,
                              hipStream_t stream) {
    const float* h   = (const float*)d_in[0];
    const float* enc = (const float*)d_in[1];
    const float* W1  = (const float*)d_in[2];
    const float* b1  = (const float*)d_in[3];
    const float* W2  = (const float*)d_in[4];
    const float* b2  = (const float*)d_in[5];
    const float* V   = (const float*)d_in[6];
    const float* bv  = (const float*)d_in[7];
    float* out = (float*)d_out;                 // [0,16384) context, [16384,81920) attn
    float* ws  = (float*)d_ws;

    float* hbp       = ws;                      // 4*16384 floats
    float* scorepart = ws + 65536;              // 8*65536 floats
    float* ctxpart   = ws + 65536 + 524288;     // 256*1024 floats
    const size_t base_bytes = (65536 + 524288 + 262144) * 4;
    short* W2T   = (short*)((char*)d_ws + base_bytes);
    short* encbf = (short*)((char*)d_ws + base_bytes + (size_t)U_ * D_ * 2);

    hb_kernel<<<256, 256, 0, stream>>>(h, W1, b1, b2, hbp);
    convert_enc<<<16384, 256, 0, stream>>>(enc, encbf);
    convert_w2t<<<256, 256, 0, stream>>>(W2, W2T);
    gemm_score_bf16<<<dim3(8, 512), 256, 0, stream>>>(encbf, W2T, hbp, V, scorepart);
    softmax_kernel<<<16, 256, 0, stream>>>(scorepart, bv, out + 16384);
    ctx_part_bf<<<256, 256, 0, stream>>>(encbf, out + 16384, ctxpart);
    ctx_reduce_kernel<<<64, 256, 0, stream>>>(ctxpart, out);
}

// Round 4
// 605.315 us; speedup vs baseline: 1.2568x; 1.0282x over previous
//
#include <hip/hip_runtime.h>
#include <hip/hip_bf16.h>
#include <math.h>

#define B_ 16
#define T_ 4096
#define D_ 1024
#define U_ 1024
#define M_ (B_*T_)   // 65536

typedef __attribute__((ext_vector_type(8))) short short8;
typedef __attribute__((ext_vector_type(4))) short short4v;
typedef __attribute__((ext_vector_type(4))) float float4v;

static __device__ __forceinline__ short f2bf(float f) {
    unsigned u = __builtin_bit_cast(unsigned, f);
    u += 0x7FFFu + ((u >> 16) & 1u);   // RNE
    return (short)(u >> 16);
}
static __device__ __forceinline__ float bf2f(short s) {
    unsigned u = ((unsigned)(unsigned short)s) << 16;
    return __builtin_bit_cast(float, u);
}
static __device__ __forceinline__ float fast_tanh(float x) {
    float c = fminf(fmaxf(2.f * x, -30.f), 30.f);
    float t = __expf(c);
    return __fdividef(t - 1.f, t + 1.f);
}

#define GLLDS(GP, LP) __builtin_amdgcn_global_load_lds( \
    (const __attribute__((address_space(1))) void*)(GP), \
    (__attribute__((address_space(3))) void*)(LP), 16, 0, 0)

// ---------------- kernel 1: hb partials, K split 4 ways
__global__ void hb_kernel(const float* __restrict__ h, const float* __restrict__ W1,
                          const float* __restrict__ b1, const float* __restrict__ b2,
                          float* __restrict__ hbp) {
    int x = blockIdx.x;                       // 256
    int kc = x >> 6;                          // 0..3
    int gid = (x & 63) * 256 + threadIdx.x;   // 0..16383
    int b = gid >> 10, u = gid & 1023;
    const float* hr = h + b * D_ + kc * 256;
    const float* w = W1 + (size_t)(kc * 256) * U_ + u;
    float s0 = 0.f, s1 = 0.f, s2 = 0.f, s3 = 0.f;
    for (int k = 0; k < 256; k += 4) {
        s0 += hr[k+0] * w[(size_t)(k+0) * U_];
        s1 += hr[k+1] * w[(size_t)(k+1) * U_];
        s2 += hr[k+2] * w[(size_t)(k+2) * U_];
        s3 += hr[k+3] * w[(size_t)(k+3) * U_];
    }
    float s = ((s0 + s1) + (s2 + s3));
    if (kc == 0) s += b1[u] + b2[u];
    hbp[kc * 16384 + gid] = s;
}

// ---------------- converters
__global__ void convert_enc(const float* __restrict__ enc, short* __restrict__ encbf) {
    size_t g = (size_t)blockIdx.x * 256 + threadIdx.x;
    const float4v* p = (const float4v*)(enc + g * 16);
    float4v f0 = p[0], f1 = p[1], f2 = p[2], f3 = p[3];
    short8 a, b;
    a[0]=f2bf(f0[0]); a[1]=f2bf(f0[1]); a[2]=f2bf(f0[2]); a[3]=f2bf(f0[3]);
    a[4]=f2bf(f1[0]); a[5]=f2bf(f1[1]); a[6]=f2bf(f1[2]); a[7]=f2bf(f1[3]);
    b[0]=f2bf(f2[0]); b[1]=f2bf(f2[1]); b[2]=f2bf(f2[2]); b[3]=f2bf(f2[3]);
    b[4]=f2bf(f3[0]); b[5]=f2bf(f3[1]); b[6]=f2bf(f3[2]); b[7]=f2bf(f3[3]);
    short8* q = (short8*)(encbf + g * 16);
    q[0] = a; q[1] = b;
}

__global__ void convert_w2t(const float* __restrict__ W2, short* __restrict__ W2T) {
    __shared__ short t[64][65];
    int k0 = (blockIdx.x >> 4) * 64, u0 = (blockIdx.x & 15) * 64;
    int tx = threadIdx.x & 63, ty = threadIdx.x >> 6;
    #pragma unroll
    for (int r = 0; r < 16; ++r) {
        int kk = ty * 16 + r;
        t[kk][tx] = f2bf(W2[(size_t)(k0 + kk) * U_ + u0 + tx]);
    }
    __syncthreads();
    #pragma unroll
    for (int r = 0; r < 16; ++r) {
        int uu = ty * 16 + r;
        W2T[(size_t)(u0 + uu) * D_ + k0 + tx] = t[tx][uu];
    }
}

// ---------------- kernel 2: bf16 GEMM + tanh·V epilogue, XCD-locality swizzle
// 1-D grid of 4096. xcd = g&7 (dispatch round-robin); per-XCD sequence q walks
// all 8 ntiles of one mtile consecutively -> one hot 256KB A-tile + 2MB W2T per L2.
__global__ __launch_bounds__(256) void gemm_score_bf16(
    const short* __restrict__ Abf,   // enc bf16 [M_, D_]
    const short* __restrict__ W2T,   // bf16 [U_, D_]
    const float* __restrict__ hbp,   // [4][B_, U_]
    const float* __restrict__ V,
    float* __restrict__ scorepart)   // [8][M_]
{
    __shared__ __align__(16) short As[128 * 32];
    __shared__ __align__(16) short Bs[128 * 32];
    __shared__ float sbuf[2][128];

    const int tid = threadIdx.x;
    const int g = blockIdx.x;
    const int c = g & 7, q = g >> 3;
    const int ntile = q & 7;
    const int mtile = (q >> 3) * 8 + c;
    const int row0 = mtile * 128, n0 = ntile * 128;
    const int bidx = row0 >> 12;

    const int lane = tid & 63, wv = tid >> 6;
    const int wm = wv >> 1, wn = wv & 1;
    const int lm = lane & 15, quad = lane >> 4;
    const int arow = tid >> 2, akq = (tid & 3) * 8;

    float4v acc[4][4] = {};

    for (int K0 = 0; K0 < D_; K0 += 32) {
        GLLDS(Abf + (size_t)(row0 + arow) * D_ + K0 + akq,       As + tid * 8);
        GLLDS(Abf + (size_t)(row0 + 64 + arow) * D_ + K0 + akq,  As + 2048 + tid * 8);
        GLLDS(W2T + (size_t)(n0 + arow) * D_ + K0 + akq,         Bs + tid * 8);
        GLLDS(W2T + (size_t)(n0 + 64 + arow) * D_ + K0 + akq,    Bs + 2048 + tid * 8);
        __syncthreads();
        short8 af[4], bfr[4];
        #pragma unroll
        for (int mi = 0; mi < 4; ++mi)
            af[mi] = *(const short8*)&As[(wm * 64 + mi * 16 + lm) * 32 + quad * 8];
        #pragma unroll
        for (int ni = 0; ni < 4; ++ni)
            bfr[ni] = *(const short8*)&Bs[(wn * 64 + ni * 16 + lm) * 32 + quad * 8];
        #pragma unroll
        for (int mi = 0; mi < 4; ++mi)
            #pragma unroll
            for (int ni = 0; ni < 4; ++ni)
                acc[mi][ni] = __builtin_amdgcn_mfma_f32_16x16x32_bf16(
                    af[mi], bfr[ni], acc[mi][ni], 0, 0, 0);
        __syncthreads();
    }

    float hbv[4], Vv[4];
    #pragma unroll
    for (int ni = 0; ni < 4; ++ni) {
        int U = n0 + wn * 64 + ni * 16 + lm;
        int o = bidx * U_ + U;
        hbv[ni] = hbp[o] + hbp[16384 + o] + hbp[32768 + o] + hbp[49152 + o];
        Vv[ni]  = V[U];
    }
    #pragma unroll
    for (int mi = 0; mi < 4; ++mi) {
        #pragma unroll
        for (int r = 0; r < 4; ++r) {
            float s = 0.f;
            #pragma unroll
            for (int ni = 0; ni < 4; ++ni)
                s += fast_tanh(acc[mi][ni][r] + hbv[ni]) * Vv[ni];
            #pragma unroll
            for (int off = 1; off < 16; off <<= 1)
                s += __shfl_xor(s, off, 64);
            if (lm == 0)
                sbuf[wn][wm * 64 + mi * 16 + quad * 4 + r] = s;
        }
    }
    __syncthreads();
    if (tid < 128)
        scorepart[(size_t)ntile * M_ + row0 + tid] = sbuf[0][tid] + sbuf[1][tid];
}

// ---------------- kernel 3: per-batch softmax over T (1024 threads)
__global__ __launch_bounds__(1024) void softmax_kernel(
        const float* __restrict__ scorepart,
        const float* __restrict__ bv,
        float* __restrict__ out_attn) {
    __shared__ float sm[T_];
    __shared__ float redm[16];
    __shared__ float reds[16];
    int b = blockIdx.x, tid = threadIdx.x;   // 0..1023
    int wv = tid >> 6;
    float bvv = bv[0];
    float lmax = -1e30f;
    #pragma unroll
    for (int i = 0; i < 4; ++i) {
        int t = tid + i * 1024;
        float s = bvv;
        #pragma unroll
        for (int p = 0; p < 8; ++p) s += scorepart[(size_t)p * M_ + b * T_ + t];
        sm[t] = s;
        lmax = fmaxf(lmax, s);
    }
    #pragma unroll
    for (int off = 1; off < 64; off <<= 1) lmax = fmaxf(lmax, __shfl_xor(lmax, off, 64));
    if ((tid & 63) == 0) redm[wv] = lmax;
    __syncthreads();
    float m = redm[0];
    #pragma unroll
    for (int j = 1; j < 16; ++j) m = fmaxf(m, redm[j]);
    float lsum = 0.f;
    #pragma unroll
    for (int i = 0; i < 4; ++i) {
        int t = tid + i * 1024;
        float e = __expf(sm[t] - m);
        sm[t] = e;
        lsum += e;
    }
    #pragma unroll
    for (int off = 1; off < 64; off <<= 1) lsum += __shfl_xor(lsum, off, 64);
    if ((tid & 63) == 0) reds[wv] = lsum;
    __syncthreads();
    float tot = 0.f;
    #pragma unroll
    for (int j = 0; j < 16; ++j) tot += reds[j];
    float rinv = 1.f / tot;
    #pragma unroll
    for (int i = 0; i < 4; ++i) {
        int t = tid + i * 1024;
        out_attn[b * T_ + t] = sm[t] * rinv;
    }
}

// ---------------- kernel 4: context partials, 512 blocks x 128-row chunks
__global__ void ctx_part_bf(const short* __restrict__ encbf,
                            const float* __restrict__ attn,
                            float* __restrict__ part) {   // [512][1024], aliases scorepart
    __shared__ float wsm[128];
    int x = blockIdx.x;               // x = tc*16 + b, tc 0..31
    int b = x & 15, tc = x >> 4;
    int tid = threadIdx.x;            // 0..255
    if (tid < 128) wsm[tid] = attn[b * T_ + tc * 128 + tid];
    __syncthreads();
    const short* e0 = encbf + (size_t)(b * T_ + tc * 128) * D_ + tid * 4;
    float4v acc = {};
    for (int t = 0; t < 128; ++t) {
        short4v v = *(const short4v*)(e0 + (size_t)t * D_);
        float w = wsm[t];
        acc[0] += w * bf2f(v[0]);
        acc[1] += w * bf2f(v[1]);
        acc[2] += w * bf2f(v[2]);
        acc[3] += w * bf2f(v[3]);
    }
    *(float4v*)(part + (size_t)x * 1024 + tid * 4) = acc;
}

// ---------------- kernel 5: reduce context partials (32 per (b,d))
__global__ void ctx_reduce_kernel(const float* __restrict__ part, float* __restrict__ ctx) {
    int gid = blockIdx.x * 256 + threadIdx.x;   // 0..16383
    int b = gid >> 10, d = gid & 1023;
    float s = 0.f;
    #pragma unroll
    for (int tc = 0; tc < 32; ++tc) s += part[(size_t)(tc * 16 + b) * 1024 + d];
    ctx[gid] = s;
}

extern "C" void kernel_launch(void* const* d_in, const int* in_sizes, int n_in,
                              void* d_out, int out_size, void* d_ws, size_t ws_size,
                              hipStream_t stream) {
    const float* h   = (const float*)d_in[0];
    const float* enc = (const float*)d_in[1];
    const float* W1  = (const float*)d_in[2];
    const float* b1  = (const float*)d_in[3];
    const float* W2  = (const float*)d_in[4];
    const float* b2  = (const float*)d_in[5];
    const float* V   = (const float*)d_in[6];
    const float* bv  = (const float*)d_in[7];
    float* out = (float*)d_out;                 // [0,16384) context, [16384,81920) attn
    float* ws  = (float*)d_ws;

    float* hbp       = ws;                      // 4*16384 floats (256 KB)
    float* scorepart = ws + 65536;              // 8*65536 floats (2 MB)
    float* ctxpart   = scorepart;               // ALIAS: reused after softmax consumes it
    short* W2T   = (short*)(ws + 65536 + 524288);          // 2 MB
    short* encbf = (short*)((char*)W2T + (size_t)U_ * D_ * 2);  // 128 MB

    hb_kernel<<<256, 256, 0, stream>>>(h, W1, b1, b2, hbp);
    convert_enc<<<16384, 256, 0, stream>>>(enc, encbf);
    convert_w2t<<<256, 256, 0, stream>>>(W2, W2T);
    gemm_score_bf16<<<4096, 256, 0, stream>>>(encbf, W2T, hbp, V, scorepart);
    softmax_kernel<<<16, 1024, 0, stream>>>(scorepart, bv, out + 16384);
    ctx_part_bf<<<512, 256, 0, stream>>>(encbf, out + 16384, ctxpart);
    ctx_reduce_kernel<<<64, 256, 0, stream>>>(ctxpart, out);
}